// Round 6
// baseline (882.992 us; speedup 1.0000x reference)
//
#include <hip/hip_runtime.h>
#include <hip/hip_cooperative_groups.h>

#define Bq 16
#define Sq 512
#define Dq 400
#define Vq 32000
#define Tq 8
#define NSq 30
#define NGq 3
#define BTq (Bq*Tq)                     // 128
#define SLICE 4096000                   // Bq*Tq*Vq, one ptr slice (elems)
#define PTR_TOTAL (30ull*SLICE)         // 122,880,000
#define GATE_TOTAL (NSq*Bq*NGq)         // 1440

// zero-fill of out ptr slices 1..29: 29*SLICE/4 = 29,696,000 float4 total.
// k_attn covers [0, AZB*ZPER); fused k_logits covers the rest (grid-stride).
#define ZTOT 29696000ull                // float4 count
#define ZPER 16384                      // float4 per k_attn zero block
#define AZB 640                         // zero blocks in k_attn (167.8 MB)
#define ZSTART (640ull*16384ull)        // 10,485,760

#define NCOMPUTE 250                    // k_logits GEMM blocks
#define NZB 262                         // k_logits zero blocks (grid = 512)
#define ZSTRIDE (NZB*256)               // 67,072 threads grid-striding

// native clang vector for nontemporal 16B stores
typedef float f4nt __attribute__((ext_vector_type(4)));

__device__ inline float sigmoidf_(float x) { return 1.0f / (1.0f + __expf(-x)); }

// round-to-nearest-even f32 -> bf16 (as ushort in low 16 bits)
__device__ inline unsigned bf16rne(float x) {
    unsigned u = __float_as_uint(x);
    return (u + 0x7FFFu + ((u >> 16) & 1u)) >> 16;
}

__device__ inline float blockReduceSum(float v, float* red) {
    int tid = threadIdx.x;
    #pragma unroll
    for (int o = 32; o > 0; o >>= 1) v += __shfl_down(v, o, 64);
    if ((tid & 63) == 0) red[tid >> 6] = v;
    __syncthreads();
    if (tid == 0) {
        float s = red[0];
        int nw = blockDim.x >> 6;
        for (int i = 1; i < nw; i++) s += red[i];
        red[0] = s;
    }
    __syncthreads();
    float r = red[0];
    __syncthreads();
    return r;
}

__device__ inline float blockReduceMax(float v, float* red) {
    int tid = threadIdx.x;
    #pragma unroll
    for (int o = 32; o > 0; o >>= 1) v = fmaxf(v, __shfl_down(v, o, 64));
    if ((tid & 63) == 0) red[tid >> 6] = v;
    __syncthreads();
    if (tid == 0) {
        float s = red[0];
        int nw = blockDim.x >> 6;
        for (int i = 1; i < nw; i++) s = fmaxf(s, red[i]);
        red[0] = s;
    }
    __syncthreads();
    float r = red[0];
    __syncthreads();
    return r;
}

// blocks [0,128): per-(b,t) fused GRU gates + elementwise + scores + softmax
// -> probs_buf + context(RAW scores) + p_gen + gate0 + hT write.
// blocks [128,128+AZB): nontemporal zero-fill 168 MB of out ptr slices.
__global__ __launch_bounds__(512) void k_attn(const float* __restrict__ enc_hidden,
                                              const float* __restrict__ shared_emb,
                                              const float* __restrict__ slot_emb,
                                              const float* __restrict__ w_ih,
                                              const float* __restrict__ w_hh,
                                              const float* __restrict__ b_ih,
                                              const float* __restrict__ b_hh,
                                              const int* __restrict__ trg,
                                              const float* __restrict__ enc_out,
                                              const int* __restrict__ story,
                                              const float* __restrict__ w_ratio_w,
                                              const float* __restrict__ w_ratio_b,
                                              const float* __restrict__ w_gate_w,
                                              const float* __restrict__ w_gate_b,
                                              float* __restrict__ probs, float* __restrict__ pgen,
                                              float* __restrict__ hT, float* __restrict__ out_gate,
                                              float* __restrict__ out) {
    int tid = threadIdx.x;
    if (blockIdx.x >= BTq) {
        int zb = blockIdx.x - BTq;                    // zero idx [0,AZB)
        f4nt z = (f4nt)(0.0f);
        f4nt* dst = (f4nt*)(out + (size_t)SLICE);
        size_t base = (size_t)zb * ZPER + tid;
        #pragma unroll
        for (int r = 0; r < ZPER / 512; ++r) {
            size_t idx = base + (size_t)r * 512;
            if (idx < ZTOT) __builtin_nontemporal_store(z, &dst[idx]);
        }
        return;
    }
    __shared__ float x_l[Dq], h0_l[Dq], h_l[Dq], ctx_l[Dq], sc_l[Sq];
    __shared__ float gi_l[1200], gh_l[1200];
    __shared__ float red[8];
    int bt = blockIdx.x, b = bt >> 3, t = bt & 7;
    if (tid < 100) {
        const float4* src = (t == 0) ? (const float4*)slot_emb
            : (const float4*)(shared_emb + (size_t)trg[b * (NSq * Tq) + (t - 1)] * Dq);
        *(float4*)&x_l[4 * tid] = src[tid];
    } else if (tid >= 256 && tid < 356) {
        int q = tid - 256;
        *(float4*)&h0_l[4 * q] = ((const float4*)(enc_hidden + b * Dq))[q];
    }
    __syncthreads();
    for (int j = tid; j < 1200; j += 512) {
        const float4* wi4 = (const float4*)(w_ih + (size_t)j * Dq);
        const float4* wh4 = (const float4*)(w_hh + (size_t)j * Dq);
        const float4* x4  = (const float4*)x_l;
        const float4* h4  = (const float4*)h0_l;
        float ai = b_ih[j], ah = b_hh[j];
        #pragma unroll 4
        for (int q = 0; q < Dq / 4; ++q) {
            float4 wv = wi4[q], av = x4[q];
            ai += av.x * wv.x + av.y * wv.y + av.z * wv.z + av.w * wv.w;
            float4 wh = wh4[q], hv = h4[q];
            ah += hv.x * wh.x + hv.y * wh.y + hv.z * wh.z + hv.w * wh.w;
        }
        gi_l[j] = ai; gh_l[j] = ah;
    }
    __syncthreads();
    if (tid < Dq) {
        int d = tid;
        float r_ = sigmoidf_(gi_l[d] + gh_l[d]);
        float z  = sigmoidf_(gi_l[Dq + d] + gh_l[Dq + d]);
        float n  = tanhf(gi_l[2 * Dq + d] + r_ * gh_l[2 * Dq + d]);
        float h  = (1.0f - z) * n + z * h0_l[d];
        h_l[d] = h;
        hT[d * BTq + bt] = h;
    }
    __syncthreads();
    {   // scores: one s per thread
        const float4* e4 = (const float4*)(enc_out + ((size_t)(b * Sq + tid)) * Dq);
        float acc = 0.0f;
        for (int q = 0; q < Dq / 4; ++q) {
            float4 p = e4[q];
            int k = 4 * q;
            acc += h_l[k]*p.x + h_l[k+1]*p.y + h_l[k+2]*p.z + h_l[k+3]*p.w;
        }
        sc_l[tid] = acc;
    }
    __syncthreads();
    float myv = sc_l[tid];
    float m = blockReduceMax(myv, red);
    float e = __expf(myv - m);
    float ssum = blockReduceSum(e, red);
    probs[bt * Sq + tid] = e / ssum;                  // scatter deferred to fused final
    for (int d = tid; d < Dq; d += 512) {             // context from RAW scores
        float acc = 0.0f;
        #pragma unroll 8
        for (int s = 0; s < Sq; ++s)
            acc += sc_l[s] * enc_out[((size_t)(b * Sq + s)) * Dq + d];
        ctx_l[d] = acc;
    }
    __syncthreads();
    {   // p_gen = sigmoid([h,ctx,X] . w_ratio + b)
        float part = 0.0f;
        for (int i = tid; i < 1200; i += 512) {
            float v = (i < Dq) ? h_l[i] : (i < 2 * Dq ? ctx_l[i - Dq] : x_l[i - 2 * Dq]);
            part += v * w_ratio_w[i];
        }
        float tot = blockReduceSum(part, red);
        if (tid == 0) pgen[bt] = sigmoidf_(tot + w_ratio_b[0]);
    }
    if (t == 0) {
        for (int g = 0; g < NGq; ++g) {
            float part = 0.0f;
            for (int d = tid; d < Dq; d += 512) part += ctx_l[d] * w_gate_w[g * Dq + d];
            float tot = blockReduceSum(part, red);
            if (tid == 0) out_gate[b * NGq + g] = tot + w_gate_b[g];
        }
    }
}

// Cooperative fused GEMM + zero-fill + grid.sync + softmax-combine-scatter.
// grid = 512 (250 GEMM + 262 zero), 256 thr, 64 KB LDS -> 2 blocks/CU.
// GEMM blocks keep bf16-rounded acc in registers across the sync, then
// normalize + scatter + stream their 128x128 tile directly to out.
#define TVL 128
#define CKL 40
__global__ __launch_bounds__(256, 2) void k_logits(const float* __restrict__ hT,
                                                   const float* __restrict__ emb,
                                                   const float* __restrict__ probs,
                                                   const int* __restrict__ story,
                                                   const float* __restrict__ pgen,
                                                   float* __restrict__ pmax,
                                                   float* __restrict__ psum,
                                                   float* __restrict__ out) {
    namespace cg = cooperative_groups;
    __shared__ __align__(16) float smem[16384];       // 64 KB: eT/hL, then chunk
    int bid = blockIdx.x;
    int tid = threadIdx.x;
    int tx = tid & 15, ty = tid >> 4;
    int v0 = bid * TVL;
    float acc[8][8];

    if (bid >= NCOMPUTE) {
        // zero-fill out ptr slices (grid-stride over [ZSTART, ZTOT))
        int zb = bid - NCOMPUTE;
        f4nt z = (f4nt)(0.0f);
        f4nt* dst = (f4nt*)(out + (size_t)SLICE);
        for (size_t idx = ZSTART + (size_t)zb * 256 + tid; idx < ZTOT; idx += ZSTRIDE)
            __builtin_nontemporal_store(z, &dst[idx]);
        if (zb == 0) {                                // gate slices 1..29
            float4 z4 = make_float4(0.0f, 0.0f, 0.0f, 0.0f);
            float4* g = (float4*)(out + PTR_TOTAL + Bq * NGq);
            for (int i = tid; i < (GATE_TOTAL - Bq * NGq) / 4; i += 256) g[i] = z4;
        }
        cg::this_grid().sync();
        return;
    }

    float (*eT)[132] = (float(*)[132])smem;           // 5280 f
    float (*hL)[132] = (float(*)[132])(smem + 5280);  // 5280 f
    #pragma unroll
    for (int j = 0; j < 8; ++j)
        #pragma unroll
        for (int i = 0; i < 8; ++i) acc[j][i] = 0.0f;

    for (int c = 0; c < Dq / CKL; ++c) {
        int k0 = c * CKL;
        const float4* hg = (const float4*)(hT + (size_t)k0 * BTq);
        #pragma unroll
        for (int r = 0; r < 5; ++r) {
            int idx = tid + 256 * r;
            int k = idx >> 5, c4 = idx & 31;
            float4 vd = hg[idx];
            *(float4*)&hL[k][4 * c4] = vd;
        }
        #pragma unroll
        for (int r = 0; r < 5; ++r) {
            int idx = tid + 256 * r;
            int v = idx / 10, q = idx - 10 * v;
            float4 vd = *(const float4*)(emb + (size_t)(v0 + v) * Dq + k0 + 4 * q);
            eT[4*q+0][v] = vd.x; eT[4*q+1][v] = vd.y; eT[4*q+2][v] = vd.z; eT[4*q+3][v] = vd.w;
        }
        __syncthreads();
        #pragma unroll 4
        for (int k = 0; k < CKL; ++k) {
            float4 h0 = *(const float4*)&hL[k][8 * ty];
            float4 h1 = *(const float4*)&hL[k][8 * ty + 4];
            float4 e0 = *(const float4*)&eT[k][8 * tx];
            float4 e1 = *(const float4*)&eT[k][8 * tx + 4];
            float hv[8] = {h0.x, h0.y, h0.z, h0.w, h1.x, h1.y, h1.z, h1.w};
            float ev[8] = {e0.x, e0.y, e0.z, e0.w, e1.x, e1.y, e1.z, e1.w};
            #pragma unroll
            for (int j = 0; j < 8; ++j)
                #pragma unroll
                for (int i = 0; i < 8; ++i)
                    acc[j][i] += hv[j] * ev[i];
        }
        __syncthreads();
    }
    // epilogue: round acc to bf16 in-register; per-row partial max/expsum
    #pragma unroll
    for (int j = 0; j < 8; ++j) {
        int bt = 8 * ty + j;
        float m = -1e30f;
        #pragma unroll
        for (int i = 0; i < 8; ++i) {
            unsigned bb = bf16rne(acc[j][i]);
            acc[j][i] = __uint_as_float(bb << 16);
            m = fmaxf(m, acc[j][i]);
        }
        #pragma unroll
        for (int o = 8; o >= 1; o >>= 1) m = fmaxf(m, __shfl_xor(m, o, 16));
        float es = 0.0f;
        #pragma unroll
        for (int i = 0; i < 8; ++i) es += __expf(acc[j][i] - m);
        #pragma unroll
        for (int o = 8; o >= 1; o >>= 1) es += __shfl_xor(es, o, 16);
        if (tx == 0) {
            pmax[bt * 256 + bid] = m;                 // transposed: coalesced stats read
            psum[bt * 256 + bid] = es;
        }
    }

    cg::this_grid().sync();

    // ---- final phase: global row stats -> normalize own tile -> scatter -> out
    {   // wave-parallel row stats into smem[0..128)=m, smem[128..256)=sum
        int wave = tid >> 6, lane = tid & 63;
        for (int r = wave; r < BTq; r += 4) {
            float pmv[4]; float m = -1e30f;
            #pragma unroll
            for (int k = 0; k < 4; ++k) {
                int idx = lane + 64 * k;
                pmv[k] = (idx < NCOMPUTE) ? pmax[r * 256 + idx] : -1e30f;
                m = fmaxf(m, pmv[k]);
            }
            #pragma unroll
            for (int o = 32; o > 0; o >>= 1) m = fmaxf(m, __shfl_xor(m, o, 64));
            float s = 0.0f;
            #pragma unroll
            for (int k = 0; k < 4; ++k) {
                int idx = lane + 64 * k;
                if (idx < NCOMPUTE) s += psum[r * 256 + idx] * __expf(pmv[k] - m);
            }
            #pragma unroll
            for (int o = 32; o > 0; o >>= 1) s += __shfl_xor(s, o, 64);
            if (lane == 0) { smem[r] = m; smem[128 + r] = s; }
        }
    }
    __syncthreads();
    float rm[8], ri[8], rpg[8];
    #pragma unroll
    for (int j = 0; j < 8; ++j) {
        int bt = 8 * ty + j;
        rm[j] = smem[bt];
        ri[j] = 1.0f / smem[128 + bt];
        rpg[j] = pgen[bt];
    }
    __syncthreads();                                  // before chunk overwrites stats
    #pragma unroll
    for (int j = 0; j < 8; ++j) {
        int bt = 8 * ty + j;
        #pragma unroll
        for (int i = 0; i < 8; ++i)
            smem[bt * 128 + 8 * tx + i] = rpg[j] * __expf(acc[j][i] - rm[j]) * ri[j];
    }
    __syncthreads();
    // scatter (1-pg)*probs for story tokens landing in this 128-v column range
    for (int r = 0; r < BTq; ++r) {
        int b = r >> 3;
        float cg = 1.0f - pgen[r];
        for (int s = tid; s < Sq; s += 256) {
            int rel = story[b * Sq + s] - v0;
            if ((unsigned)rel < 128u)
                atomicAdd(&smem[r * 128 + rel], cg * probs[r * Sq + s]);
        }
    }
    __syncthreads();
    for (int i = tid; i < BTq * 32; i += 256) {       // 4096 float4
        int r = i >> 5, q = i & 31;
        f4nt v = *(f4nt*)&smem[r * 128 + 4 * q];
        __builtin_nontemporal_store(v, (f4nt*)(out + (size_t)r * Vq + v0 + 4 * q));
    }
}

extern "C" void kernel_launch(void* const* d_in, const int* in_sizes, int n_in,
                              void* d_out, int out_size, void* d_ws, size_t ws_size,
                              hipStream_t stream) {
    const float* enc_hidden = (const float*)d_in[0];
    const float* enc_out    = (const float*)d_in[1];
    const int*   story      = (const int*)d_in[2];
    const int*   trg        = (const int*)d_in[3];
    const float* shared_emb = (const float*)d_in[4];
    const float* slot_emb   = (const float*)d_in[5];
    const float* w_ih       = (const float*)d_in[6];
    const float* w_hh       = (const float*)d_in[7];
    const float* b_ih       = (const float*)d_in[8];
    const float* b_hh       = (const float*)d_in[9];
    const float* w_ratio_w  = (const float*)d_in[10];
    const float* w_ratio_b  = (const float*)d_in[11];
    const float* w_gate_w   = (const float*)d_in[12];
    const float* w_gate_b   = (const float*)d_in[13];

    float* out = (float*)d_out;

    // scratch in d_ws
    float* ws = (float*)d_ws;
    float* probs_buf = ws;                         // 65,536 f (128 x 512)
    float* hT_buf    = probs_buf + 65536;          // 51,200 f
    float* pgen_buf  = hT_buf + 51200;             // 128 f
    float* pmax_buf  = pgen_buf + 128;             // 32,768 f (128 x 256)
    float* psum_buf  = pmax_buf + 32768;           // 32,768 f

    hipLaunchKernelGGL(k_attn, dim3(BTq + AZB), dim3(512), 0, stream,
                       enc_hidden, shared_emb, slot_emb, w_ih, w_hh, b_ih, b_hh, trg,
                       enc_out, story, w_ratio_w, w_ratio_b, w_gate_w, w_gate_b,
                       probs_buf, pgen_buf, hT_buf, out + PTR_TOTAL, out);

    void* args[] = {(void*)&hT_buf, (void*)&shared_emb, (void*)&probs_buf,
                    (void*)&story, (void*)&pgen_buf, (void*)&pmax_buf,
                    (void*)&psum_buf, (void*)&out};
    hipLaunchCooperativeKernel((const void*)k_logits, dim3(NCOMPUTE + NZB), dim3(256),
                               args, 0, stream);
}

// Round 7
// 722.687 us; speedup vs baseline: 1.2218x; 1.2218x over previous
//
#include <hip/hip_runtime.h>

#define Bq 16
#define Sq 512
#define Dq 400
#define Vq 32000
#define Tq 8
#define NSq 30
#define NGq 3
#define BTq (Bq*Tq)                     // 128
#define SLICE 4096000                   // Bq*Tq*Vq, one ptr slice (elems)
#define PTR_TOTAL (30ull*SLICE)         // 122,880,000
#define GATE_TOTAL (NSq*Bq*NGq)         // 1440

// zero-fill of out ptr slices 1..29: 29*SLICE/4 = 29,696,000 float4 total.
// k_gru covers zb [0,AZB1); k_logits covers [AZB1,1813); last k_logits block
// zeroes the gate slices.
#define ZTOT 29696000ull                // float4 count
#define ZPER 16384                      // float4 per zero block
#define AZB1 400                        // zero blocks in k_gru (104.9 MB)
#define LZB2 1413                       // zero blocks in k_logits (1813-400)

#define NCOMPUTE 250                    // k_logits GEMM blocks
#define NATTN 128                       // k_logits attn2 blocks

// k_final: 8 blocks per bt row, single streaming pass
#define FBLK 8
#define FCH (Vq/FBLK)                   // 4000 v per block

// native clang vector for nontemporal 16B stores
typedef float f4nt __attribute__((ext_vector_type(4)));

__device__ inline float sigmoidf_(float x) { return 1.0f / (1.0f + __expf(-x)); }

// round-to-nearest-even f32 -> bf16 (as ushort in low 16 bits)
__device__ inline unsigned bf16rne(float x) {
    unsigned u = __float_as_uint(x);
    return (u + 0x7FFFu + ((u >> 16) & 1u)) >> 16;
}

__device__ inline float blockReduceSum(float v, float* red) {
    int tid = threadIdx.x;
    #pragma unroll
    for (int o = 32; o > 0; o >>= 1) v += __shfl_down(v, o, 64);
    if ((tid & 63) == 0) red[tid >> 6] = v;
    __syncthreads();
    if (tid == 0) {
        float s = red[0];
        int nw = blockDim.x >> 6;
        for (int i = 1; i < nw; i++) s += red[i];
        red[0] = s;
    }
    __syncthreads();
    float r = red[0];
    __syncthreads();
    return r;
}

__device__ inline float blockReduceMax(float v, float* red) {
    int tid = threadIdx.x;
    #pragma unroll
    for (int o = 32; o > 0; o >>= 1) v = fmaxf(v, __shfl_down(v, o, 64));
    if ((tid & 63) == 0) red[tid >> 6] = v;
    __syncthreads();
    if (tid == 0) {
        float s = red[0];
        int nw = blockDim.x >> 6;
        for (int i = 1; i < nw; i++) s = fmaxf(s, red[i]);
        red[0] = s;
    }
    __syncthreads();
    float r = red[0];
    __syncthreads();
    return r;
}

// blocks [0,128): per-(b,t) GRU gates (from w_ih/w_hh via L2) + elementwise;
// writes hT (transposed, for GEMM) and hB (row-major, for attn2).
// blocks [128,128+AZB1): nontemporal zero-fill of out ptr slices.
__global__ __launch_bounds__(512) void k_gru(const float* __restrict__ enc_hidden,
                                             const float* __restrict__ shared_emb,
                                             const float* __restrict__ slot_emb,
                                             const float* __restrict__ w_ih,
                                             const float* __restrict__ w_hh,
                                             const float* __restrict__ b_ih,
                                             const float* __restrict__ b_hh,
                                             const int* __restrict__ trg,
                                             float* __restrict__ hT, float* __restrict__ hB,
                                             float* __restrict__ out) {
    int tid = threadIdx.x;
    if (blockIdx.x >= BTq) {
        int zb = blockIdx.x - BTq;                    // zero idx [0,AZB1)
        f4nt z = (f4nt)(0.0f);
        f4nt* dst = (f4nt*)(out + (size_t)SLICE);
        size_t base = (size_t)zb * ZPER + tid;
        #pragma unroll
        for (int r = 0; r < ZPER / 512; ++r) {
            size_t idx = base + (size_t)r * 512;
            if (idx < ZTOT) __builtin_nontemporal_store(z, &dst[idx]);
        }
        return;
    }
    __shared__ float x_l[Dq], h0_l[Dq];
    __shared__ float gi_l[1200], gh_l[1200];
    int bt = blockIdx.x, b = bt >> 3, t = bt & 7;
    if (tid < 100) {
        const float4* src = (t == 0) ? (const float4*)slot_emb
            : (const float4*)(shared_emb + (size_t)trg[b * (NSq * Tq) + (t - 1)] * Dq);
        *(float4*)&x_l[4 * tid] = src[tid];
    } else if (tid >= 256 && tid < 356) {
        int q = tid - 256;
        *(float4*)&h0_l[4 * q] = ((const float4*)(enc_hidden + b * Dq))[q];
    }
    __syncthreads();
    for (int j = tid; j < 1200; j += 512) {
        const float4* wi4 = (const float4*)(w_ih + (size_t)j * Dq);
        const float4* wh4 = (const float4*)(w_hh + (size_t)j * Dq);
        const float4* x4  = (const float4*)x_l;
        const float4* h4  = (const float4*)h0_l;
        float ai = b_ih[j], ah = b_hh[j];
        #pragma unroll 4
        for (int q = 0; q < Dq / 4; ++q) {
            float4 wv = wi4[q], av = x4[q];
            ai += av.x * wv.x + av.y * wv.y + av.z * wv.z + av.w * wv.w;
            float4 wh = wh4[q], hv = h4[q];
            ah += hv.x * wh.x + hv.y * wh.y + hv.z * wh.z + hv.w * wh.w;
        }
        gi_l[j] = ai; gh_l[j] = ah;
    }
    __syncthreads();
    if (tid < Dq) {
        int d = tid;
        float r_ = sigmoidf_(gi_l[d] + gh_l[d]);
        float z  = sigmoidf_(gi_l[Dq + d] + gh_l[Dq + d]);
        float n  = tanhf(gi_l[2 * Dq + d] + r_ * gh_l[2 * Dq + d]);
        float h  = (1.0f - z) * n + z * h0_l[d];
        hT[d * BTq + bt] = h;
        hB[bt * Dq + d]  = h;
    }
}

// Fused: [0,250) logits GEMM (bf16 logits + per-block softmax partials);
// [250,378) attn2 per-(b,t): scores+softmax->probs, context, p_gen, gate0;
// [378,378+LZB2) nontemporal zero-fill; last block zeroes gate slices 1..29.
#define TVL 128
#define CKL 40
__global__ __launch_bounds__(256) void k_logits(const float* __restrict__ hT,
                                                const float* __restrict__ emb,
                                                const float* __restrict__ hB,
                                                const float* __restrict__ slot_emb,
                                                const int* __restrict__ trg,
                                                const float* __restrict__ enc_out,
                                                const float* __restrict__ w_ratio_w,
                                                const float* __restrict__ w_ratio_b,
                                                const float* __restrict__ w_gate_w,
                                                const float* __restrict__ w_gate_b,
                                                float* __restrict__ probs,
                                                float* __restrict__ pgen,
                                                float* __restrict__ out_gate,
                                                unsigned short* __restrict__ logits,
                                                float* __restrict__ pmax,
                                                float* __restrict__ psum,
                                                float* __restrict__ out) {
    __shared__ __align__(16) float smem[10560];       // GEMM: eT+hL; attn2 carve-out
    int bid = blockIdx.x;
    int tid = threadIdx.x;

    if (bid >= NCOMPUTE) {
        int r0 = bid - NCOMPUTE;
        if (r0 < NATTN) {
            // ---- attn2: one (b,t) per block, 256 threads ----
            float* h_l  = smem;                       // 400
            float* ctx_l= smem + 400;                 // 400
            float* x_l  = smem + 800;                 // 400
            float* sc_l = smem + 1200;                // 512
            float* red  = smem + 1712;                // 8
            int bt = r0, b = bt >> 3, t = bt & 7;
            if (tid < 100) {
                *(float4*)&h_l[4 * tid] = ((const float4*)(hB + (size_t)bt * Dq))[tid];
            } else if (tid < 200) {
                int q = tid - 100;
                const float4* src = (t == 0) ? (const float4*)slot_emb
                    : (const float4*)(emb + (size_t)trg[b * (NSq * Tq) + (t - 1)] * Dq);
                *(float4*)&x_l[4 * q] = src[q];
            }
            __syncthreads();
            for (int s = tid; s < Sq; s += 256) {     // scores: 2 per thread
                const float4* e4 = (const float4*)(enc_out + ((size_t)(b * Sq + s)) * Dq);
                float acc = 0.0f;
                for (int q = 0; q < Dq / 4; ++q) {
                    float4 p = e4[q];
                    int k = 4 * q;
                    acc += h_l[k]*p.x + h_l[k+1]*p.y + h_l[k+2]*p.z + h_l[k+3]*p.w;
                }
                sc_l[s] = acc;
            }
            __syncthreads();
            float v0 = sc_l[tid], v1 = sc_l[tid + 256];
            float m = blockReduceMax(fmaxf(v0, v1), red);
            float e0 = __expf(v0 - m), e1 = __expf(v1 - m);
            float ssum = blockReduceSum(e0 + e1, red);
            probs[bt * Sq + tid]       = e0 / ssum;
            probs[bt * Sq + tid + 256] = e1 / ssum;
            for (int d = tid; d < Dq; d += 256) {     // context from RAW scores
                float acc = 0.0f;
                #pragma unroll 8
                for (int s = 0; s < Sq; ++s)
                    acc += sc_l[s] * enc_out[((size_t)(b * Sq + s)) * Dq + d];
                ctx_l[d] = acc;
            }
            __syncthreads();
            {   // p_gen = sigmoid([h,ctx,X] . w_ratio + b)
                float part = 0.0f;
                for (int i = tid; i < 1200; i += 256) {
                    float v = (i < Dq) ? h_l[i] : (i < 2 * Dq ? ctx_l[i - Dq] : x_l[i - 2 * Dq]);
                    part += v * w_ratio_w[i];
                }
                float tot = blockReduceSum(part, red);
                if (tid == 0) pgen[bt] = sigmoidf_(tot + w_ratio_b[0]);
            }
            if (t == 0) {
                for (int g = 0; g < NGq; ++g) {
                    float part = 0.0f;
                    for (int d = tid; d < Dq; d += 256) part += ctx_l[d] * w_gate_w[g * Dq + d];
                    float tot = blockReduceSum(part, red);
                    if (tid == 0) out_gate[b * NGq + g] = tot + w_gate_b[g];
                }
            }
            return;
        }
        int zl = r0 - NATTN;
        if (zl < LZB2) {
            int zb = AZB1 + zl;                       // global zero idx
            f4nt z = (f4nt)(0.0f);
            f4nt* dst = (f4nt*)(out + (size_t)SLICE);
            size_t base = (size_t)zb * ZPER + tid;
            #pragma unroll
            for (int r = 0; r < ZPER / 256; ++r) {
                size_t idx = base + (size_t)r * 256;
                if (idx < ZTOT) __builtin_nontemporal_store(z, &dst[idx]);
            }
        } else {
            float4 z4 = make_float4(0.0f, 0.0f, 0.0f, 0.0f);
            float4* g = (float4*)(out + PTR_TOTAL + Bq * NGq);
            for (int i = tid; i < (GATE_TOTAL - Bq * NGq) / 4; i += 256) g[i] = z4;
        }
        return;
    }

    // ---- GEMM blocks ----
    float (*eT)[132] = (float(*)[132])smem;           // 5280 f
    float (*hL)[132] = (float(*)[132])(smem + 5280);  // 5280 f
    int v0 = bid * TVL;
    int tx = tid & 15, ty = tid >> 4;
    float acc[8][8];
    #pragma unroll
    for (int j = 0; j < 8; ++j)
        #pragma unroll
        for (int i = 0; i < 8; ++i) acc[j][i] = 0.0f;

    for (int c = 0; c < Dq / CKL; ++c) {
        int k0 = c * CKL;
        const float4* hg = (const float4*)(hT + (size_t)k0 * BTq);
        #pragma unroll
        for (int r = 0; r < 5; ++r) {
            int idx = tid + 256 * r;
            int k = idx >> 5, c4 = idx & 31;
            float4 vd = hg[idx];
            *(float4*)&hL[k][4 * c4] = vd;
        }
        #pragma unroll
        for (int r = 0; r < 5; ++r) {
            int idx = tid + 256 * r;
            int v = idx / 10, q = idx - 10 * v;
            float4 vd = *(const float4*)(emb + (size_t)(v0 + v) * Dq + k0 + 4 * q);
            eT[4*q+0][v] = vd.x; eT[4*q+1][v] = vd.y; eT[4*q+2][v] = vd.z; eT[4*q+3][v] = vd.w;
        }
        __syncthreads();
        #pragma unroll 4
        for (int k = 0; k < CKL; ++k) {
            float4 h0 = *(const float4*)&hL[k][8 * ty];
            float4 h1 = *(const float4*)&hL[k][8 * ty + 4];
            float4 e0 = *(const float4*)&eT[k][8 * tx];
            float4 e1 = *(const float4*)&eT[k][8 * tx + 4];
            float hv[8] = {h0.x, h0.y, h0.z, h0.w, h1.x, h1.y, h1.z, h1.w};
            float ev[8] = {e0.x, e0.y, e0.z, e0.w, e1.x, e1.y, e1.z, e1.w};
            #pragma unroll
            for (int j = 0; j < 8; ++j)
                #pragma unroll
                for (int i = 0; i < 8; ++i)
                    acc[j][i] += hv[j] * ev[i];
        }
        __syncthreads();
    }
    // epilogue: round to bf16, per-row partial max/expsum, pack+store
    #pragma unroll
    for (int j = 0; j < 8; ++j) {
        int bt = 8 * ty + j;
        unsigned bb[8];
        float r[8];
        float m = -1e30f;
        #pragma unroll
        for (int i = 0; i < 8; ++i) {
            bb[i] = bf16rne(acc[j][i]);
            r[i] = __uint_as_float(bb[i] << 16);
            m = fmaxf(m, r[i]);
        }
        #pragma unroll
        for (int o = 8; o >= 1; o >>= 1) m = fmaxf(m, __shfl_xor(m, o, 16));
        float es = 0.0f;
        #pragma unroll
        for (int i = 0; i < 8; ++i) es += __expf(r[i] - m);
        #pragma unroll
        for (int o = 8; o >= 1; o >>= 1) es += __shfl_xor(es, o, 16);
        if (tx == 0) {
            pmax[bid * BTq + bt] = m;
            psum[bid * BTq + bt] = es;
        }
        uint4 w = make_uint4(bb[0] | (bb[1] << 16), bb[2] | (bb[3] << 16),
                             bb[4] | (bb[5] << 16), bb[6] | (bb[7] << 16));
        *(uint4*)(logits + (size_t)bt * Vq + v0 + 8 * tx) = w;
    }
}

// single streaming pass: finalize (m,s) from 250 partials; build the 4000-v
// chunk in LDS (pg*softmax), scatter-add (1-pg)*probs via story tokens (LDS
// atomics handle duplicates), then one coalesced nontemporal write. 1024 blocks.
__global__ __launch_bounds__(256) void k_final(const unsigned short* __restrict__ logits,
                                               const float* __restrict__ probs,
                                               const int* __restrict__ story,
                                               const float* __restrict__ pgen,
                                               const float* __restrict__ pmax,
                                               const float* __restrict__ psum,
                                               float* __restrict__ out) {
    __shared__ float chunk[FCH];                      // 16 KB
    __shared__ float red[4];
    int bid = blockIdx.x, tid = threadIdx.x;
    int bt = bid >> 3, ch = bid & 7, b = bt >> 3;
    float pm = (tid < NCOMPUTE) ? pmax[tid * BTq + bt] : -1e30f;
    float m = blockReduceMax(pm, red);
    float part = (tid < NCOMPUTE) ? psum[tid * BTq + bt] * __expf(pm - m) : 0.0f;
    float s = blockReduceSum(part, red);
    float inv = 1.0f / s, pg = pgen[bt], cg = 1.0f - pg;
    int lo = ch * FCH;
    const uint4* l4 = (const uint4*)(logits + (size_t)bt * Vq + lo);  // 500 uint4
    for (int i = tid; i < FCH / 8; i += 256) {
        uint4 lv = l4[i];
        float f0 = __uint_as_float(lv.x << 16), f1 = __uint_as_float(lv.x & 0xFFFF0000u);
        float f2 = __uint_as_float(lv.y << 16), f3 = __uint_as_float(lv.y & 0xFFFF0000u);
        float f4 = __uint_as_float(lv.z << 16), f5 = __uint_as_float(lv.z & 0xFFFF0000u);
        float f6 = __uint_as_float(lv.w << 16), f7 = __uint_as_float(lv.w & 0xFFFF0000u);
        chunk[8 * i + 0] = pg * __expf(f0 - m) * inv;
        chunk[8 * i + 1] = pg * __expf(f1 - m) * inv;
        chunk[8 * i + 2] = pg * __expf(f2 - m) * inv;
        chunk[8 * i + 3] = pg * __expf(f3 - m) * inv;
        chunk[8 * i + 4] = pg * __expf(f4 - m) * inv;
        chunk[8 * i + 5] = pg * __expf(f5 - m) * inv;
        chunk[8 * i + 6] = pg * __expf(f6 - m) * inv;
        chunk[8 * i + 7] = pg * __expf(f7 - m) * inv;
    }
    __syncthreads();
    for (int ss = tid; ss < Sq; ss += 256) {
        int rel = story[b * Sq + ss] - lo;
        if (rel >= 0 && rel < FCH)
            atomicAdd(&chunk[rel], cg * probs[bt * Sq + ss]);
    }
    __syncthreads();
    f4nt* o4 = (f4nt*)(out + (size_t)bt * Vq + lo);
    const f4nt* c4 = (const f4nt*)chunk;
    for (int i = tid; i < FCH / 4; i += 256)
        __builtin_nontemporal_store(c4[i], &o4[i]);
}

extern "C" void kernel_launch(void* const* d_in, const int* in_sizes, int n_in,
                              void* d_out, int out_size, void* d_ws, size_t ws_size,
                              hipStream_t stream) {
    const float* enc_hidden = (const float*)d_in[0];
    const float* enc_out    = (const float*)d_in[1];
    const int*   story      = (const int*)d_in[2];
    const int*   trg        = (const int*)d_in[3];
    const float* shared_emb = (const float*)d_in[4];
    const float* slot_emb   = (const float*)d_in[5];
    const float* w_ih       = (const float*)d_in[6];
    const float* w_hh       = (const float*)d_in[7];
    const float* b_ih       = (const float*)d_in[8];
    const float* b_hh       = (const float*)d_in[9];
    const float* w_ratio_w  = (const float*)d_in[10];
    const float* w_ratio_b  = (const float*)d_in[11];
    const float* w_gate_w   = (const float*)d_in[12];
    const float* w_gate_b   = (const float*)d_in[13];

    float* out = (float*)d_out;

    // scratch in d_ws
    float* ws = (float*)d_ws;
    unsigned short* logits_buf = (unsigned short*)ws;  // 4,096,000 bf16 (8.2 MB)
    float* probs_buf = ws + (size_t)SLICE;         // 65,536 f (128 x 512)
    float* hT_buf    = probs_buf + 65536;          // 51,200 f
    float* hB_buf    = hT_buf + 51200;             // 51,200 f
    float* pgen_buf  = hB_buf + 51200;             // 128 f
    float* pmax_buf  = pgen_buf + 128;             // 32,000 f (250 x 128)
    float* psum_buf  = pmax_buf + 32000;           // 32,000 f

    hipLaunchKernelGGL(k_gru, dim3(BTq + AZB1), dim3(512), 0, stream,
                       enc_hidden, shared_emb, slot_emb, w_ih, w_hh, b_ih, b_hh, trg,
                       hT_buf, hB_buf, out);
    hipLaunchKernelGGL(k_logits, dim3(NCOMPUTE + NATTN + LZB2 + 1), dim3(256), 0, stream,
                       hT_buf, shared_emb, hB_buf, slot_emb, trg, enc_out,
                       w_ratio_w, w_ratio_b, w_gate_w, w_gate_b,
                       probs_buf, pgen_buf, out + PTR_TOTAL,
                       logits_buf, pmax_buf, psum_buf, out);
    hipLaunchKernelGGL(k_final, dim3(BTq * FBLK), dim3(256), 0, stream,
                       logits_buf, probs_buf, story, pgen_buf, pmax_buf, psum_buf, out);
}